// Round 1
// baseline (1792.096 us; speedup 1.0000x reference)
//
#include <hip/hip_runtime.h>
#include <cstdint>
#include <cstddef>

#define NR 8192
#define KD 512

// ---- workspace byte offsets ----
#define OFF_CN   0u          // 4096 f32 coarse codebook norms
#define OFF_FN   16384u      // 8192 f32 fine codebook norms
#define OFF_ZN   49152u      // 8192 f32 z-coarse row norms
#define OFF_RN   81920u      // 8192 f32 residual row norms
#define OFF_LOSS 114688u     // 1 f32 loss accumulator
#define OFF_AMC  114944u     // 8192 u64 coarse argmin keys
#define OFF_AMF  180480u     // 8192 u64 fine argmin keys
#define OFF_H    246272u     // 8192*512 f32 MLP pre-LN output (reused for both MLPs)
#define OFF_INFL 17023488u   // 8192*512 f32 coarse_influence
// total = 33,800,704 bytes

__device__ __forceinline__ float block_sum(float v, float* sred) {
#pragma unroll
  for (int off = 32; off > 0; off >>= 1) v += __shfl_down(v, off, 64);
  if ((threadIdx.x & 63) == 0) sred[threadIdx.x >> 6] = v;
  __syncthreads();
  float r = sred[0] + sred[1] + sred[2] + sred[3];
  __syncthreads();
  return r;
}

__device__ __forceinline__ float sigmoidf_(float x) { return 1.0f / (1.0f + expf(-x)); }

// ---- K0: row norms for coarse emb / fine emb / z-coarse; zero loss ----
__global__ __launch_bounds__(256) void row_norms(const float* __restrict__ ce,
                                                 const float* __restrict__ fe,
                                                 const float* __restrict__ z,
                                                 float* __restrict__ cn, float* __restrict__ fn,
                                                 float* __restrict__ zn, float* __restrict__ lossp) {
  __shared__ float sred[4];
  const int b = blockIdx.x, t = threadIdx.x;
  const float* src;
  float* dst;
  if (b < 4096) {
    src = ce + (size_t)b * KD; dst = cn + b;
  } else if (b < 12288) {
    src = fe + (size_t)(b - 4096) * KD; dst = fn + (b - 4096);
  } else {
    src = z + (size_t)(b - 12288) * 1024; dst = zn + (b - 12288);
  }
  float v0 = src[t], v1 = src[t + 256];
  float s = block_sum(v0 * v0 + v1 * v1, sred);
  if (t == 0) {
    dst[0] = s;
    if (b == 0) lossp[0] = 0.0f;
  }
}

// ---- generic 64x64xK tiled fp32 GEMM (C = A * B^T), fused epilogues ----
// aMode: 0 = A[row*lda + aOff + k]
//        1 = A[gather_idx(row)*512 + k]            (gather low 32 bits of amin key)
//        2 = z[row*1024 + 512 + k] - gc*infl[row*512 + k]   (on-the-fly residual)
// eMode: 0 = argmin epilogue: d = (rowNorm + colNorm) - 2*acc -> atomicMin key
//        1 = store epilogue:  C[row*512 + col] = acc + bias[col]
__global__ __launch_bounds__(256) void vq_gemm(
    const float* __restrict__ A, int lda, int aOff, int aMode,
    const unsigned long long* __restrict__ gather,
    const float* __restrict__ infl, const float* __restrict__ gRaw,
    const float* __restrict__ B,
    const float* __restrict__ rowNorm, const float* __restrict__ colNorm,
    unsigned long long* __restrict__ amin,
    const float* __restrict__ bias, float* __restrict__ C, int eMode) {
  __shared__ float As[32][68];
  __shared__ float Bs[32][68];
  const int t = threadIdx.x;
  const int rowTile = blockIdx.y << 6;
  const int colTile = blockIdx.x << 6;
  const int r0 = t >> 3;        // 0..31
  const int r1 = r0 + 32;       // 32..63
  const int c4 = (t & 7) << 2;  // 0..28 step 4

  const float* aP0;
  const float* aP1;
  const float* iP0 = nullptr;
  const float* iP1 = nullptr;
  float gc = 0.0f;
  if (aMode == 0) {
    aP0 = A + (size_t)(rowTile + r0) * lda + aOff;
    aP1 = A + (size_t)(rowTile + r1) * lda + aOff;
  } else if (aMode == 1) {
    unsigned i0 = (unsigned)(gather[rowTile + r0] & 0xffffffffULL);
    unsigned i1 = (unsigned)(gather[rowTile + r1] & 0xffffffffULL);
    aP0 = A + (size_t)i0 * KD;
    aP1 = A + (size_t)i1 * KD;
  } else {
    gc = sigmoidf_(gRaw[0]);
    aP0 = A + (size_t)(rowTile + r0) * 1024 + 512;
    aP1 = A + (size_t)(rowTile + r1) * 1024 + 512;
    iP0 = infl + (size_t)(rowTile + r0) * KD;
    iP1 = infl + (size_t)(rowTile + r1) * KD;
  }
  const float* bP0 = B + (size_t)(colTile + r0) * KD;
  const float* bP1 = B + (size_t)(colTile + r1) * KD;

  const int ty = (t >> 4) << 2;  // tile-row base (0..60)
  const int tx = (t & 15) << 2;  // tile-col base (0..60)

  float acc[4][4] = {{0.0f}};

  for (int kk = 0; kk < KD; kk += 32) {
    float4 a0, a1, b0, b1;
    if (aMode == 2) {
      float4 z0 = *(const float4*)(aP0 + kk + c4);
      float4 z1 = *(const float4*)(aP1 + kk + c4);
      float4 f0 = *(const float4*)(iP0 + kk + c4);
      float4 f1 = *(const float4*)(iP1 + kk + c4);
      a0 = make_float4(z0.x - gc * f0.x, z0.y - gc * f0.y, z0.z - gc * f0.z, z0.w - gc * f0.w);
      a1 = make_float4(z1.x - gc * f1.x, z1.y - gc * f1.y, z1.z - gc * f1.z, z1.w - gc * f1.w);
    } else {
      a0 = *(const float4*)(aP0 + kk + c4);
      a1 = *(const float4*)(aP1 + kk + c4);
    }
    b0 = *(const float4*)(bP0 + kk + c4);
    b1 = *(const float4*)(bP1 + kk + c4);
    __syncthreads();  // previous iteration's compute done before overwrite
    As[c4 + 0][r0] = a0.x; As[c4 + 1][r0] = a0.y; As[c4 + 2][r0] = a0.z; As[c4 + 3][r0] = a0.w;
    As[c4 + 0][r1] = a1.x; As[c4 + 1][r1] = a1.y; As[c4 + 2][r1] = a1.z; As[c4 + 3][r1] = a1.w;
    Bs[c4 + 0][r0] = b0.x; Bs[c4 + 1][r0] = b0.y; Bs[c4 + 2][r0] = b0.z; Bs[c4 + 3][r0] = b0.w;
    Bs[c4 + 0][r1] = b1.x; Bs[c4 + 1][r1] = b1.y; Bs[c4 + 2][r1] = b1.z; Bs[c4 + 3][r1] = b1.w;
    __syncthreads();
#pragma unroll
    for (int k = 0; k < 32; ++k) {
      float4 av = *(const float4*)(&As[k][ty]);
      float4 bv = *(const float4*)(&Bs[k][tx]);
      acc[0][0] += av.x * bv.x; acc[0][1] += av.x * bv.y; acc[0][2] += av.x * bv.z; acc[0][3] += av.x * bv.w;
      acc[1][0] += av.y * bv.x; acc[1][1] += av.y * bv.y; acc[1][2] += av.y * bv.z; acc[1][3] += av.y * bv.w;
      acc[2][0] += av.z * bv.x; acc[2][1] += av.z * bv.y; acc[2][2] += av.z * bv.z; acc[2][3] += av.z * bv.w;
      acc[3][0] += av.w * bv.x; acc[3][1] += av.w * bv.y; acc[3][2] += av.w * bv.z; acc[3][3] += av.w * bv.w;
    }
  }

  const int row0 = rowTile + ty;
  const int col0 = colTile + tx;
  if (eMode == 0) {
    float cn0 = colNorm[col0], cn1 = colNorm[col0 + 1], cn2 = colNorm[col0 + 2], cn3 = colNorm[col0 + 3];
#pragma unroll
    for (int r = 0; r < 4; ++r) {
      float xn = rowNorm[row0 + r];
      // mimic numpy: (||x||^2 + ||e||^2) - 2*(x.e), same rounding structure
      float d0 = (xn + cn0) - 2.0f * acc[r][0];
      float d1 = (xn + cn1) - 2.0f * acc[r][1];
      float d2 = (xn + cn2) - 2.0f * acc[r][2];
      float d3 = (xn + cn3) - 2.0f * acc[r][3];
      float best = d0; int bi = col0;
      if (d1 < best) { best = d1; bi = col0 + 1; }
      if (d2 < best) { best = d2; bi = col0 + 2; }
      if (d3 < best) { best = d3; bi = col0 + 3; }
      unsigned ub = __float_as_uint(best);
      ub = (ub & 0x80000000u) ? ~ub : (ub | 0x80000000u);  // monotonic float->u32
      unsigned long long key = ((unsigned long long)ub << 32) | (unsigned long long)(unsigned)bi;
#pragma unroll
      for (int off = 1; off < 16; off <<= 1) {
        unsigned long long o = __shfl_xor(key, off, 64);
        if (o < key) key = o;
      }
      if ((t & 15) == 0) atomicMin(amin + row0 + r, key);
    }
  } else {
    float4 b4 = *(const float4*)(bias + col0);
#pragma unroll
    for (int r = 0; r < 4; ++r) {
      float4 o = make_float4(acc[r][0] + b4.x, acc[r][1] + b4.y, acc[r][2] + b4.z, acc[r][3] + b4.w);
      *(float4*)(C + (size_t)(row0 + r) * KD + col0) = o;
    }
  }
}

// ---- K4: LayerNorm + leaky -> influence; residual row norms ----
__global__ __launch_bounds__(256) void ln_residual(
    const float* __restrict__ h, const float* __restrict__ g, const float* __restrict__ be,
    const float* __restrict__ z, const float* __restrict__ gRaw,
    float* __restrict__ infl, float* __restrict__ rn) {
  __shared__ float sred[4];
  const int row = blockIdx.x, t = threadIdx.x;
  const size_t base = (size_t)row * KD;
  float h0 = h[base + t], h1 = h[base + t + 256];
  float m = block_sum(h0 + h1, sred) * (1.0f / 512.0f);
  float d0 = h0 - m, d1 = h1 - m;
  float var = block_sum(d0 * d0 + d1 * d1, sred) * (1.0f / 512.0f);
  float sq = sqrtf(var + 1e-5f);
  float gc = sigmoidf_(gRaw[0]);
  float v0 = d0 / sq * g[t] + be[t];
  float v1 = d1 / sq * g[t + 256] + be[t + 256];
  v0 = v0 > 0.0f ? v0 : 0.1f * v0;
  v1 = v1 > 0.0f ? v1 : 0.1f * v1;
  infl[base + t] = v0;
  infl[base + t + 256] = v1;
  float zf0 = z[(size_t)row * 1024 + 512 + t];
  float zf1 = z[(size_t)row * 1024 + 512 + t + 256];
  float r0 = zf0 - gc * v0, r1 = zf1 - gc * v1;
  float rs = block_sum(r0 * r0 + r1 * r1, sred);
  if (t == 0) rn[row] = rs;
}

// ---- K8: LN+leaky on h2, gather q_c/q_f, outputs + loss partials ----
__global__ __launch_bounds__(256) void finalize(
    const float* __restrict__ h, const float* __restrict__ g, const float* __restrict__ be,
    const float* __restrict__ infl,
    const unsigned long long* __restrict__ amc, const unsigned long long* __restrict__ amf,
    const float* __restrict__ z, const float* __restrict__ ce, const float* __restrict__ fe,
    const float* __restrict__ gcRaw, const float* __restrict__ gfRaw,
    float* __restrict__ out, float* __restrict__ lossp) {
  __shared__ float sred[4];
  const int row = blockIdx.x, t = threadIdx.x;
  const size_t base = (size_t)row * KD;
  float h0 = h[base + t], h1 = h[base + t + 256];
  float m = block_sum(h0 + h1, sred) * (1.0f / 512.0f);
  float d0 = h0 - m, d1 = h1 - m;
  float var = block_sum(d0 * d0 + d1 * d1, sred) * (1.0f / 512.0f);
  float sq = sqrtf(var + 1e-5f);
  float fb0 = d0 / sq * g[t] + be[t];
  float fb1 = d1 / sq * g[t + 256] + be[t + 256];
  fb0 = fb0 > 0.0f ? fb0 : 0.1f * fb0;
  fb1 = fb1 > 0.0f ? fb1 : 0.1f * fb1;
  float gc = sigmoidf_(gcRaw[0]);
  float gf = sigmoidf_(gfRaw[0]);
  unsigned ic = (unsigned)(amc[row] & 0xffffffffULL);
  unsigned ifx = (unsigned)(amf[row] & 0xffffffffULL);
  float loc = 0.0f;
#pragma unroll
  for (int j = 0; j < 2; ++j) {
    int c = t + j * 256;
    float fb = j ? fb1 : fb0;
    float qc = ce[(size_t)ic * KD + c];
    float qf = fe[(size_t)ifx * KD + c];
    float zc = z[(size_t)row * 1024 + c];
    float zf = z[(size_t)row * 1024 + 512 + c];
    float fl = infl[base + c];
    out[(size_t)row * 1024 + c] = qc + 0.1f * gf * fb;
    out[(size_t)row * 1024 + 512 + c] = qf + gc * fl;
    float dc = qc - zc;
    float res = zf - gc * fl;
    float df = qf - res;
    loc += dc * dc + df * df;
  }
  float ls = block_sum(loc, sred);
  if (t == 0) atomicAdd(lossp, ls);
}

__global__ void loss_write(const float* __restrict__ lossp, float* __restrict__ out) {
  out[0] = 1.25f * lossp[0] / (8192.0f * 512.0f);
}

extern "C" void kernel_launch(void* const* d_in, const int* in_sizes, int n_in,
                              void* d_out, int out_size, void* d_ws, size_t ws_size,
                              hipStream_t stream) {
  const float* z      = (const float*)d_in[0];
  const float* ce     = (const float*)d_in[1];
  const float* fe     = (const float*)d_in[2];
  const float* w_c2f  = (const float*)d_in[3];
  const float* b_c2f  = (const float*)d_in[4];
  const float* g_c2f  = (const float*)d_in[5];
  const float* be_c2f = (const float*)d_in[6];
  const float* w_f2c  = (const float*)d_in[7];
  const float* b_f2c  = (const float*)d_in[8];
  const float* g_f2c  = (const float*)d_in[9];
  const float* be_f2c = (const float*)d_in[10];
  const float* gcRaw  = (const float*)d_in[11];
  const float* gfRaw  = (const float*)d_in[12];
  float* out = (float*)d_out;
  char* ws = (char*)d_ws;

  float* cn = (float*)(ws + OFF_CN);
  float* fn = (float*)(ws + OFF_FN);
  float* zn = (float*)(ws + OFF_ZN);
  float* rn = (float*)(ws + OFF_RN);
  float* lossp = (float*)(ws + OFF_LOSS);
  unsigned long long* amc = (unsigned long long*)(ws + OFF_AMC);
  unsigned long long* amf = (unsigned long long*)(ws + OFF_AMF);
  float* h = (float*)(ws + OFF_H);
  float* infl = (float*)(ws + OFF_INFL);

  // init argmin keys (coarse+fine contiguous) to u64 max
  hipMemsetAsync(ws + OFF_AMC, 0xFF, 131072, stream);

  // norms (coarse emb, fine emb, z-coarse rows) + zero loss
  row_norms<<<20480, 256, 0, stream>>>(ce, fe, z, cn, fn, zn, lossp);

  // coarse VQ: 8192x4096x512, argmin
  vq_gemm<<<dim3(64, 128), 256, 0, stream>>>(z, 1024, 0, 0, nullptr, nullptr, nullptr,
                                             ce, zn, cn, amc, nullptr, nullptr, 0);
  // MLP1: h = q_c @ w_c2f^T + b  (gather q_c rows from coarse emb)
  vq_gemm<<<dim3(8, 128), 256, 0, stream>>>(ce, 512, 0, 1, amc, nullptr, nullptr,
                                            w_c2f, nullptr, nullptr, nullptr, b_c2f, h, 1);
  // LN + leaky -> influence; residual norms
  ln_residual<<<8192, 256, 0, stream>>>(h, g_c2f, be_c2f, z, gcRaw, infl, rn);

  // fine VQ: residual (on the fly) vs fine emb, 8192x8192x512, argmin
  vq_gemm<<<dim3(128, 128), 256, 0, stream>>>(z, 1024, 0, 2, nullptr, infl, gcRaw,
                                              fe, rn, fn, amf, nullptr, nullptr, 0);
  // MLP2: h = q_f @ w_f2c^T + b  (gather q_f rows from fine emb)
  vq_gemm<<<dim3(8, 128), 256, 0, stream>>>(fe, 512, 0, 1, amf, nullptr, nullptr,
                                            w_f2c, nullptr, nullptr, nullptr, b_f2c, h, 1);
  // outputs + loss
  finalize<<<8192, 256, 0, stream>>>(h, g_f2c, be_f2c, infl, amc, amf, z, ce, fe,
                                     gcRaw, gfRaw, out, lossp);
  loss_write<<<1, 1, 0, stream>>>(lossp, out + (size_t)8192 * 1024);
}

// Round 2
// 808.351 us; speedup vs baseline: 2.2170x; 2.2170x over previous
//
#include <hip/hip_runtime.h>
#include <hip/hip_bf16.h>
#include <cstdint>
#include <cstddef>

#define NR 8192
#define KD 512

// ---- workspace byte offsets ----
#define OFF_CN   0u           // 4096 f32 coarse codebook norms
#define OFF_FN   16384u       // 8192 f32 fine codebook norms
#define OFF_ZN   49152u       // 8192 f32 z-coarse row norms
#define OFF_RN   81920u       // 8192 f32 residual row norms
#define OFF_LOSS 114688u      // 1 f32 loss accumulator
#define OFF_AMC  114944u      // 8192 u64 coarse argmin keys
#define OFF_AMF  180480u      // 8192 u64 fine argmin keys
#define OFF_H    246016u      // 8192*512 f32 MLP pre-LN output (reused)
#define OFF_INFL 17023232u    // 8192*512 f32 coarse_influence
#define OFF_CEH  33800448u    // 4096*512 bf16 coarse emb hi
#define OFF_CEL  37994752u    // 4096*512 bf16 coarse emb lo
#define OFF_FEH  42189056u    // 8192*512 bf16 fine emb hi
#define OFF_FEL  50577664u    // 8192*512 bf16 fine emb lo
#define OFF_ZCH  58966272u    // 8192*512 bf16 z-coarse hi
#define OFF_ZCL  67354880u    // 8192*512 bf16 z-coarse lo
#define OFF_RH   75743488u    // 8192*512 bf16 residual hi
#define OFF_RL   84132096u    // 8192*512 bf16 residual lo
// total = 92,520,704 bytes

typedef __attribute__((ext_vector_type(8))) short bf16x8;
typedef __attribute__((ext_vector_type(4))) float f32x4;

__device__ __forceinline__ float block_sum(float v, float* sred) {
#pragma unroll
  for (int off = 32; off > 0; off >>= 1) v += __shfl_down(v, off, 64);
  if ((threadIdx.x & 63) == 0) sred[threadIdx.x >> 6] = v;
  __syncthreads();
  float r = sred[0] + sred[1] + sred[2] + sred[3];
  __syncthreads();
  return r;
}

__device__ __forceinline__ float sigmoidf_(float x) { return 1.0f / (1.0f + expf(-x)); }

__device__ __forceinline__ void split_bf16(float v, __hip_bfloat16* hi, __hip_bfloat16* lo) {
  __hip_bfloat16 h = __float2bfloat16(v);
  *hi = h;
  *lo = __float2bfloat16(v - __bfloat162float(h));
}

// ---- K0: norms + bf16 hi/lo conversion for ce / fe / z-coarse; zero loss ----
__global__ __launch_bounds__(256) void prep(
    const float* __restrict__ ce, const float* __restrict__ fe, const float* __restrict__ z,
    float* __restrict__ cn, float* __restrict__ fn, float* __restrict__ zn,
    __hip_bfloat16* __restrict__ ceH, __hip_bfloat16* __restrict__ ceL,
    __hip_bfloat16* __restrict__ feH, __hip_bfloat16* __restrict__ feL,
    __hip_bfloat16* __restrict__ zcH, __hip_bfloat16* __restrict__ zcL,
    float* __restrict__ lossp) {
  __shared__ float sred[4];
  const int b = blockIdx.x, t = threadIdx.x;
  const float* src;
  float* nd;
  __hip_bfloat16 *dh, *dl;
  size_t row;
  if (b < 4096) {
    src = ce + (size_t)b * KD; nd = cn + b; dh = ceH; dl = ceL; row = b;
  } else if (b < 12288) {
    src = fe + (size_t)(b - 4096) * KD; nd = fn + (b - 4096); dh = feH; dl = feL; row = b - 4096;
  } else {
    src = z + (size_t)(b - 12288) * 1024; nd = zn + (b - 12288); dh = zcH; dl = zcL; row = b - 12288;
  }
  float acc = 0.0f;
#pragma unroll
  for (int j = 0; j < 2; ++j) {
    int c = t + j * 256;
    float v = src[c];
    acc += v * v;
    __hip_bfloat16 h, l;
    split_bf16(v, &h, &l);
    dh[row * KD + c] = h;
    dl[row * KD + c] = l;
  }
  float s = block_sum(acc, sred);
  if (t == 0) {
    nd[0] = s;
    if (b == 0) lossp[0] = 0.0f;
  }
}

// ---- MFMA VQ GEMM: D = A*B^T via bf16 hi/lo x3, fused argmin epilogue ----
// A: M x 512 (hi/lo bf16, packed lda=512), B: N x 512 (hi/lo bf16)
// 128x128 tile per block, 256 threads = 4 waves in 2x2, 16x16x32 MFMA.
__global__ __launch_bounds__(256) void vq_mfma(
    const __hip_bfloat16* __restrict__ Ah, const __hip_bfloat16* __restrict__ Al,
    const __hip_bfloat16* __restrict__ Bh, const __hip_bfloat16* __restrict__ Bl,
    const float* __restrict__ rowNorm, const float* __restrict__ colNorm,
    unsigned long long* __restrict__ amin) {
  __shared__ __align__(16) __hip_bfloat16 sAh[128 * 32];
  __shared__ __align__(16) __hip_bfloat16 sAl[128 * 32];
  __shared__ __align__(16) __hip_bfloat16 sBh[128 * 32];
  __shared__ __align__(16) __hip_bfloat16 sBl[128 * 32];
  const int t = threadIdx.x;
  const int w = t >> 6, l = t & 63;
  const int rowTile = blockIdx.y << 7;
  const int colTile = blockIdx.x << 7;
  const int wr = (w >> 1) << 6;  // wave row base in tile (0/64)
  const int wc = (w & 1) << 6;   // wave col base in tile (0/64)

  // staging: lane l covers row (l>>2) of a 16-row group, k-bytes [(l&3)*16,+16)
  const int sr = l >> 2;
  const int sk = (l & 3) << 3;  // k element offset

  f32x4 acc[4][4];
#pragma unroll
  for (int i = 0; i < 4; ++i)
#pragma unroll
    for (int j = 0; j < 4; ++j) acc[i][j] = (f32x4){0.f, 0.f, 0.f, 0.f};

  const int fr = l & 15;        // fragment row-in-16
  const int kq = (l >> 4) << 3; // fragment k offset (quad*8)

  for (int kk = 0; kk < KD; kk += 32) {
    __syncthreads();  // previous chunk's ds_reads done before overwrite
#pragma unroll
    for (int i = 0; i < 2; ++i) {
      const int rg = (w << 5) + (i << 4);  // 16-row group base (0..112)
      const size_t ga = (size_t)(rowTile + rg + sr) * KD + kk + sk;
      const size_t gb = (size_t)(colTile + rg + sr) * KD + kk + sk;
      const int lo = rg << 5;  // element offset of LDS dest base
      __builtin_amdgcn_global_load_lds(
          (const __attribute__((address_space(1))) unsigned*)(Ah + ga),
          (__attribute__((address_space(3))) unsigned*)(sAh + lo), 16, 0, 0);
      __builtin_amdgcn_global_load_lds(
          (const __attribute__((address_space(1))) unsigned*)(Al + ga),
          (__attribute__((address_space(3))) unsigned*)(sAl + lo), 16, 0, 0);
      __builtin_amdgcn_global_load_lds(
          (const __attribute__((address_space(1))) unsigned*)(Bh + gb),
          (__attribute__((address_space(3))) unsigned*)(sBh + lo), 16, 0, 0);
      __builtin_amdgcn_global_load_lds(
          (const __attribute__((address_space(1))) unsigned*)(Bl + gb),
          (__attribute__((address_space(3))) unsigned*)(sBl + lo), 16, 0, 0);
    }
    __syncthreads();  // staging complete (vmcnt drained by barrier)

    bf16x8 afh[4], afl[4], bfh[4], bfl[4];
#pragma unroll
    for (int mt = 0; mt < 4; ++mt) {
      const int ra = (wr + (mt << 4) + fr) << 5;
      afh[mt] = *(const bf16x8*)(sAh + ra + kq);
      afl[mt] = *(const bf16x8*)(sAl + ra + kq);
    }
#pragma unroll
    for (int nt = 0; nt < 4; ++nt) {
      const int rb = (wc + (nt << 4) + fr) << 5;
      bfh[nt] = *(const bf16x8*)(sBh + rb + kq);
      bfl[nt] = *(const bf16x8*)(sBl + rb + kq);
    }
#pragma unroll
    for (int mt = 0; mt < 4; ++mt)
#pragma unroll
      for (int nt = 0; nt < 4; ++nt) {
        acc[mt][nt] = __builtin_amdgcn_mfma_f32_16x16x32_bf16(afh[mt], bfh[nt], acc[mt][nt], 0, 0, 0);
        acc[mt][nt] = __builtin_amdgcn_mfma_f32_16x16x32_bf16(afh[mt], bfl[nt], acc[mt][nt], 0, 0, 0);
        acc[mt][nt] = __builtin_amdgcn_mfma_f32_16x16x32_bf16(afl[mt], bfh[nt], acc[mt][nt], 0, 0, 0);
      }
  }

  // epilogue: d = rowNorm + colNorm - 2*dot -> per-row argmin -> atomicMin key
  // C/D layout: col = lane&15, row = (lane>>4)*4 + reg
  const int quad = l >> 4;
#pragma unroll
  for (int mt = 0; mt < 4; ++mt) {
#pragma unroll
    for (int reg = 0; reg < 4; ++reg) {
      const int row = rowTile + wr + (mt << 4) + (quad << 2) + reg;
      const float xn = rowNorm[row];
      unsigned long long key = ~0ULL;
#pragma unroll
      for (int nt = 0; nt < 4; ++nt) {
        const int col = colTile + wc + (nt << 4) + fr;
        float d = (xn + colNorm[col]) - 2.0f * acc[mt][nt][reg];
        unsigned ub = __float_as_uint(d);
        ub = (ub & 0x80000000u) ? ~ub : (ub | 0x80000000u);  // monotonic float->u32
        unsigned long long k2 = ((unsigned long long)ub << 32) | (unsigned long long)(unsigned)col;
        if (k2 < key) key = k2;
      }
#pragma unroll
      for (int off = 1; off < 16; off <<= 1) {
        unsigned long long o = __shfl_xor(key, off, 64);
        if (o < key) key = o;
      }
      if (fr == 0) atomicMin(amin + row, key);
    }
  }
}

// ---- fp32 64x64 tiled GEMM, gather-A + bias epilogue (MLPs) ----
__global__ __launch_bounds__(256) void mlp_gemm(
    const float* __restrict__ A,  // codebook, lda=512
    const unsigned long long* __restrict__ gather,
    const float* __restrict__ B,
    const float* __restrict__ bias, float* __restrict__ C) {
  __shared__ float As[32][68];
  __shared__ float Bs[32][68];
  const int t = threadIdx.x;
  const int rowTile = blockIdx.y << 6;
  const int colTile = blockIdx.x << 6;
  const int r0 = t >> 3;
  const int r1 = r0 + 32;
  const int c4 = (t & 7) << 2;

  unsigned i0 = (unsigned)(gather[rowTile + r0] & 0xffffffffULL);
  unsigned i1 = (unsigned)(gather[rowTile + r1] & 0xffffffffULL);
  const float* aP0 = A + (size_t)i0 * KD;
  const float* aP1 = A + (size_t)i1 * KD;
  const float* bP0 = B + (size_t)(colTile + r0) * KD;
  const float* bP1 = B + (size_t)(colTile + r1) * KD;

  const int ty = (t >> 4) << 2;
  const int tx = (t & 15) << 2;

  float acc[4][4] = {{0.0f}};

  for (int kk = 0; kk < KD; kk += 32) {
    float4 a0 = *(const float4*)(aP0 + kk + c4);
    float4 a1 = *(const float4*)(aP1 + kk + c4);
    float4 b0 = *(const float4*)(bP0 + kk + c4);
    float4 b1 = *(const float4*)(bP1 + kk + c4);
    __syncthreads();
    As[c4 + 0][r0] = a0.x; As[c4 + 1][r0] = a0.y; As[c4 + 2][r0] = a0.z; As[c4 + 3][r0] = a0.w;
    As[c4 + 0][r1] = a1.x; As[c4 + 1][r1] = a1.y; As[c4 + 2][r1] = a1.z; As[c4 + 3][r1] = a1.w;
    Bs[c4 + 0][r0] = b0.x; Bs[c4 + 1][r0] = b0.y; Bs[c4 + 2][r0] = b0.z; Bs[c4 + 3][r0] = b0.w;
    Bs[c4 + 0][r1] = b1.x; Bs[c4 + 1][r1] = b1.y; Bs[c4 + 2][r1] = b1.z; Bs[c4 + 3][r1] = b1.w;
    __syncthreads();
#pragma unroll
    for (int k = 0; k < 32; ++k) {
      float4 av = *(const float4*)(&As[k][ty]);
      float4 bv = *(const float4*)(&Bs[k][tx]);
      acc[0][0] += av.x * bv.x; acc[0][1] += av.x * bv.y; acc[0][2] += av.x * bv.z; acc[0][3] += av.x * bv.w;
      acc[1][0] += av.y * bv.x; acc[1][1] += av.y * bv.y; acc[1][2] += av.y * bv.z; acc[1][3] += av.y * bv.w;
      acc[2][0] += av.z * bv.x; acc[2][1] += av.z * bv.y; acc[2][2] += av.z * bv.z; acc[2][3] += av.z * bv.w;
      acc[3][0] += av.w * bv.x; acc[3][1] += av.w * bv.y; acc[3][2] += av.w * bv.z; acc[3][3] += av.w * bv.w;
    }
  }

  const int row0 = rowTile + ty;
  const int col0 = colTile + tx;
  float4 b4 = *(const float4*)(bias + col0);
#pragma unroll
  for (int r = 0; r < 4; ++r) {
    float4 o = make_float4(acc[r][0] + b4.x, acc[r][1] + b4.y, acc[r][2] + b4.z, acc[r][3] + b4.w);
    *(float4*)(C + (size_t)(row0 + r) * KD + col0) = o;
  }
}

// ---- LayerNorm + leaky -> influence; residual (fp32 norms + bf16 hi/lo) ----
__global__ __launch_bounds__(256) void ln_residual(
    const float* __restrict__ h, const float* __restrict__ g, const float* __restrict__ be,
    const float* __restrict__ z, const float* __restrict__ gRaw,
    float* __restrict__ infl, float* __restrict__ rn,
    __hip_bfloat16* __restrict__ rH, __hip_bfloat16* __restrict__ rL) {
  __shared__ float sred[4];
  const int row = blockIdx.x, t = threadIdx.x;
  const size_t base = (size_t)row * KD;
  float h0 = h[base + t], h1 = h[base + t + 256];
  float m = block_sum(h0 + h1, sred) * (1.0f / 512.0f);
  float d0 = h0 - m, d1 = h1 - m;
  float var = block_sum(d0 * d0 + d1 * d1, sred) * (1.0f / 512.0f);
  float sq = sqrtf(var + 1e-5f);
  float gc = sigmoidf_(gRaw[0]);
  float v0 = d0 / sq * g[t] + be[t];
  float v1 = d1 / sq * g[t + 256] + be[t + 256];
  v0 = v0 > 0.0f ? v0 : 0.1f * v0;
  v1 = v1 > 0.0f ? v1 : 0.1f * v1;
  infl[base + t] = v0;
  infl[base + t + 256] = v1;
  float zf0 = z[(size_t)row * 1024 + 512 + t];
  float zf1 = z[(size_t)row * 1024 + 512 + t + 256];
  float r0 = zf0 - gc * v0, r1 = zf1 - gc * v1;
  __hip_bfloat16 hh, ll;
  split_bf16(r0, &hh, &ll);
  rH[base + t] = hh; rL[base + t] = ll;
  split_bf16(r1, &hh, &ll);
  rH[base + t + 256] = hh; rL[base + t + 256] = ll;
  float rs = block_sum(r0 * r0 + r1 * r1, sred);
  if (t == 0) rn[row] = rs;
}

// ---- LN+leaky on h2, gather q_c/q_f, outputs + loss partials ----
__global__ __launch_bounds__(256) void finalize(
    const float* __restrict__ h, const float* __restrict__ g, const float* __restrict__ be,
    const float* __restrict__ infl,
    const unsigned long long* __restrict__ amc, const unsigned long long* __restrict__ amf,
    const float* __restrict__ z, const float* __restrict__ ce, const float* __restrict__ fe,
    const float* __restrict__ gcRaw, const float* __restrict__ gfRaw,
    float* __restrict__ out, float* __restrict__ lossp) {
  __shared__ float sred[4];
  const int row = blockIdx.x, t = threadIdx.x;
  const size_t base = (size_t)row * KD;
  float h0 = h[base + t], h1 = h[base + t + 256];
  float m = block_sum(h0 + h1, sred) * (1.0f / 512.0f);
  float d0 = h0 - m, d1 = h1 - m;
  float var = block_sum(d0 * d0 + d1 * d1, sred) * (1.0f / 512.0f);
  float sq = sqrtf(var + 1e-5f);
  float fb0 = d0 / sq * g[t] + be[t];
  float fb1 = d1 / sq * g[t + 256] + be[t + 256];
  fb0 = fb0 > 0.0f ? fb0 : 0.1f * fb0;
  fb1 = fb1 > 0.0f ? fb1 : 0.1f * fb1;
  float gc = sigmoidf_(gcRaw[0]);
  float gf = sigmoidf_(gfRaw[0]);
  unsigned ic = (unsigned)(amc[row] & 0xffffffffULL);
  unsigned ifx = (unsigned)(amf[row] & 0xffffffffULL);
  float loc = 0.0f;
#pragma unroll
  for (int j = 0; j < 2; ++j) {
    int c = t + j * 256;
    float fb = j ? fb1 : fb0;
    float qc = ce[(size_t)ic * KD + c];
    float qf = fe[(size_t)ifx * KD + c];
    float zc = z[(size_t)row * 1024 + c];
    float zf = z[(size_t)row * 1024 + 512 + c];
    float fl = infl[base + c];
    out[(size_t)row * 1024 + c] = qc + 0.1f * gf * fb;
    out[(size_t)row * 1024 + 512 + c] = qf + gc * fl;
    float dc = qc - zc;
    float res = zf - gc * fl;
    float df = qf - res;
    loc += dc * dc + df * df;
  }
  float ls = block_sum(loc, sred);
  if (t == 0) atomicAdd(lossp, ls);
}

__global__ void loss_write(const float* __restrict__ lossp, float* __restrict__ out) {
  out[0] = 1.25f * lossp[0] / (8192.0f * 512.0f);
}

extern "C" void kernel_launch(void* const* d_in, const int* in_sizes, int n_in,
                              void* d_out, int out_size, void* d_ws, size_t ws_size,
                              hipStream_t stream) {
  const float* z      = (const float*)d_in[0];
  const float* ce     = (const float*)d_in[1];
  const float* fe     = (const float*)d_in[2];
  const float* w_c2f  = (const float*)d_in[3];
  const float* b_c2f  = (const float*)d_in[4];
  const float* g_c2f  = (const float*)d_in[5];
  const float* be_c2f = (const float*)d_in[6];
  const float* w_f2c  = (const float*)d_in[7];
  const float* b_f2c  = (const float*)d_in[8];
  const float* g_f2c  = (const float*)d_in[9];
  const float* be_f2c = (const float*)d_in[10];
  const float* gcRaw  = (const float*)d_in[11];
  const float* gfRaw  = (const float*)d_in[12];
  float* out = (float*)d_out;
  char* ws = (char*)d_ws;

  float* cn = (float*)(ws + OFF_CN);
  float* fn = (float*)(ws + OFF_FN);
  float* zn = (float*)(ws + OFF_ZN);
  float* rn = (float*)(ws + OFF_RN);
  float* lossp = (float*)(ws + OFF_LOSS);
  unsigned long long* amc = (unsigned long long*)(ws + OFF_AMC);
  unsigned long long* amf = (unsigned long long*)(ws + OFF_AMF);
  float* h = (float*)(ws + OFF_H);
  float* infl = (float*)(ws + OFF_INFL);
  __hip_bfloat16* ceH = (__hip_bfloat16*)(ws + OFF_CEH);
  __hip_bfloat16* ceL = (__hip_bfloat16*)(ws + OFF_CEL);
  __hip_bfloat16* feH = (__hip_bfloat16*)(ws + OFF_FEH);
  __hip_bfloat16* feL = (__hip_bfloat16*)(ws + OFF_FEL);
  __hip_bfloat16* zcH = (__hip_bfloat16*)(ws + OFF_ZCH);
  __hip_bfloat16* zcL = (__hip_bfloat16*)(ws + OFF_ZCL);
  __hip_bfloat16* rH  = (__hip_bfloat16*)(ws + OFF_RH);
  __hip_bfloat16* rL  = (__hip_bfloat16*)(ws + OFF_RL);

  // init argmin keys (coarse+fine contiguous) to u64 max
  hipMemsetAsync(ws + OFF_AMC, 0xFF, 131072, stream);

  // norms + bf16 hi/lo conversion (ce, fe, z-coarse); zero loss
  prep<<<20480, 256, 0, stream>>>(ce, fe, z, cn, fn, zn,
                                  ceH, ceL, feH, feL, zcH, zcL, lossp);

  // coarse VQ: 8192x4096x512 MFMA bf16x3, argmin
  vq_mfma<<<dim3(32, 64), 256, 0, stream>>>(zcH, zcL, ceH, ceL, zn, cn, amc);

  // MLP1: h = q_c @ w_c2f^T + b (gather q_c rows from coarse emb)
  mlp_gemm<<<dim3(8, 128), 256, 0, stream>>>(ce, amc, w_c2f, b_c2f, h);

  // LN + leaky -> influence; residual norms + bf16 hi/lo
  ln_residual<<<8192, 256, 0, stream>>>(h, g_c2f, be_c2f, z, gcRaw, infl, rn, rH, rL);

  // fine VQ: 8192x8192x512 MFMA bf16x3, argmin
  vq_mfma<<<dim3(64, 64), 256, 0, stream>>>(rH, rL, feH, feL, rn, fn, amf);

  // MLP2: h = q_f @ w_f2c^T + b (gather q_f rows from fine emb)
  mlp_gemm<<<dim3(8, 128), 256, 0, stream>>>(fe, amf, w_f2c, b_f2c, h);

  // outputs + loss
  finalize<<<8192, 256, 0, stream>>>(h, g_f2c, be_f2c, infl, amc, amf, z, ce, fe,
                                     gcRaw, gfRaw, out, lossp);
  loss_write<<<1, 1, 0, stream>>>(lossp, out + (size_t)8192 * 1024);
}